// Round 2
// baseline (1464.817 us; speedup 1.0000x reference)
//
#include <hip/hip_runtime.h>
#include <hip/hip_bf16.h>
#include <math.h>

typedef __bf16 bf16;
typedef __attribute__((ext_vector_type(8))) __bf16 bf16x8;
typedef __attribute__((ext_vector_type(4))) __bf16 bf16x4;
typedef __attribute__((ext_vector_type(4))) float f32x4;

#define B_N 131072
#define D_N 512
#define S_N 64
#define H_N 128

#define MFMA(a, b, c) __builtin_amdgcn_mfma_f32_16x16x32_bf16((a), (b), (c), 0, 0, 0)

// Fragment load from row-major bf16 [*, ld]. A-op: row = M row; B-op from B^T
// stored [N][K]: row = N row. lane m/n = lane&15, k = k0 + (lane>>4)*8.
__device__ __forceinline__ bf16x8 ldfrag(const bf16* __restrict__ base, int ld,
                                         int row, int k0, int lane) {
  return *(const bf16x8*)(base + (size_t)(row + (lane & 15)) * ld + k0 + ((lane >> 4) << 3));
}

// Same fragment, but source is row-major FP32: two float4 loads + cvt to bf16.
__device__ __forceinline__ bf16x8 ldfrag_f32(const float* __restrict__ base, int ld,
                                             int row, int k0, int lane) {
  const float* p = base + (size_t)(row + (lane & 15)) * ld + k0 + ((lane >> 4) << 3);
  float4 a = *(const float4*)p;
  float4 b = *(const float4*)(p + 4);
  bf16x8 r;
  r[0] = (bf16)a.x; r[1] = (bf16)a.y; r[2] = (bf16)a.z; r[3] = (bf16)a.w;
  r[4] = (bf16)b.x; r[5] = (bf16)b.y; r[6] = (bf16)b.z; r[7] = (bf16)b.w;
  return r;
}

// ---------------- pack: fp32 [R][C] -> transposed bf16 [C][R] ----------------
__global__ void ktr(const float* __restrict__ src, bf16* __restrict__ dst, int R, int C) {
  int i = blockIdx.x * 256 + threadIdx.x;
  if (i < R * C) {
    int r = i / C, c = i - r * C;
    dst[c * R + r] = (bf16)src[i];
  }
}

// ---------------- kernel 1: x -> h -> softmax weights -> sel ----------------
// grid 1024, 256 threads (4 waves), tile = 128 batch rows. LDS is wave-private.
__global__ __launch_bounds__(256, 2) void k1(
    const float* __restrict__ x, const bf16* __restrict__ w1T, const float* __restrict__ b1,
    const bf16* __restrict__ w2T, const float* __restrict__ b2,
    const bf16* __restrict__ refT, float* __restrict__ sel_out, bf16* __restrict__ sw_t) {
  __shared__ bf16 hbuf[128 * 136];   // [batch][h_idx]
  __shared__ bf16 swbuf[128 * 72];   // [batch][state]

  const int tid = threadIdx.x;
  const int wave = tid >> 6, lane = tid & 63;
  const int col = lane & 15, quad = lane >> 4;
  const int row0 = blockIdx.x * 128;
  const int bbase = wave * 32;  // this wave's 32 batch rows within the tile

  // ---- Stage 1: hT = w1T @ x^T   (M=h 128, N=batch 32/wave, K=512)
  f32x4 acc1[8][2];
#pragma unroll
  for (int mt = 0; mt < 8; mt++)
#pragma unroll
    for (int nt = 0; nt < 2; nt++) acc1[mt][nt] = (f32x4){0.f, 0.f, 0.f, 0.f};

  for (int k0 = 0; k0 < 512; k0 += 32) {
    bf16x8 bfr[2];
#pragma unroll
    for (int nt = 0; nt < 2; nt++)
      bfr[nt] = ldfrag_f32(x, D_N, row0 + bbase + nt * 16, k0, lane);
#pragma unroll
    for (int mt = 0; mt < 8; mt++) {
      bf16x8 afr = ldfrag(w1T, D_N, mt * 16, k0, lane);
      acc1[mt][0] = MFMA(afr, bfr[0], acc1[mt][0]);
      acc1[mt][1] = MFMA(afr, bfr[1], acc1[mt][1]);
    }
  }
  // bias + relu, store h row-major [batch][h] (4 consecutive h per lane)
#pragma unroll
  for (int nt = 0; nt < 2; nt++) {
    int batch = bbase + nt * 16 + col;
#pragma unroll
    for (int mt = 0; mt < 8; mt++) {
      int h0 = mt * 16 + quad * 4;
      bf16x4 pk;
#pragma unroll
      for (int r = 0; r < 4; r++) {
        float v = acc1[mt][nt][r] + b1[h0 + r];
        pk[r] = (bf16)fmaxf(v, 0.f);
      }
      *(bf16x4*)&hbuf[batch * 136 + h0] = pk;
    }
  }
  // (no barrier: hbuf/swbuf regions are wave-private)

  // ---- Stage 2: logitsT = w2T @ h^T  (M=state 64, N=batch 32/wave, K=128)
  f32x4 acc2[4][2];
#pragma unroll
  for (int mt = 0; mt < 4; mt++)
#pragma unroll
    for (int nt = 0; nt < 2; nt++) acc2[mt][nt] = (f32x4){0.f, 0.f, 0.f, 0.f};

  for (int k0 = 0; k0 < 128; k0 += 32) {
    bf16x8 bfr[2];
#pragma unroll
    for (int nt = 0; nt < 2; nt++) {
      int batch = bbase + nt * 16 + col;
      bfr[nt] = *(const bf16x8*)&hbuf[batch * 136 + k0 + quad * 8];
    }
#pragma unroll
    for (int mt = 0; mt < 4; mt++) {
      bf16x8 afr = ldfrag(w2T, H_N, mt * 16, k0, lane);
      acc2[mt][0] = MFMA(afr, bfr[0], acc2[mt][0]);
      acc2[mt][1] = MFMA(afr, bfr[1], acc2[mt][1]);
    }
  }

  // ---- softmax over 64 states per batch column (quads hold disjoint states)
#pragma unroll
  for (int nt = 0; nt < 2; nt++) {
    int batch = bbase + nt * 16 + col;
    float v[16];
#pragma unroll
    for (int mt = 0; mt < 4; mt++)
#pragma unroll
      for (int r = 0; r < 4; r++)
        v[mt * 4 + r] = acc2[mt][nt][r] + b2[mt * 16 + quad * 4 + r];
    float mx = v[0];
#pragma unroll
    for (int i = 1; i < 16; i++) mx = fmaxf(mx, v[i]);
    mx = fmaxf(mx, __shfl_xor(mx, 16));
    mx = fmaxf(mx, __shfl_xor(mx, 32));
    float s = 0.f;
#pragma unroll
    for (int i = 0; i < 16; i++) {
      v[i] = __expf(v[i] - mx);
      s += v[i];
    }
    s += __shfl_xor(s, 16);
    s += __shfl_xor(s, 32);
    float inv = 1.f / s;
#pragma unroll
    for (int mt = 0; mt < 4; mt++) {
      int s0 = mt * 16 + quad * 4;
      bf16x4 pk;
#pragma unroll
      for (int r = 0; r < 4; r++) pk[r] = (bf16)(v[mt * 4 + r] * inv);
      *(bf16x4*)&swbuf[batch * 72 + s0] = pk;
#pragma unroll
      for (int r = 0; r < 4; r++)
        sw_t[(size_t)(s0 + r) * B_N + row0 + batch] = pk[r];
    }
  }

  // ---- Stage 3: sel = sw @ ref  (M=batch 32/wave, N=512 in 4 chunks, K=64)
  for (int c = 0; c < 4; c++) {
    int d0 = c * 128;
    f32x4 acc3[2][8];
#pragma unroll
    for (int mt = 0; mt < 2; mt++)
#pragma unroll
      for (int nt = 0; nt < 8; nt++) acc3[mt][nt] = (f32x4){0.f, 0.f, 0.f, 0.f};
#pragma unroll
    for (int k0 = 0; k0 < 64; k0 += 32) {
      bf16x8 afr[2];
#pragma unroll
      for (int mt = 0; mt < 2; mt++) {
        int batch = bbase + mt * 16 + col;
        afr[mt] = *(const bf16x8*)&swbuf[batch * 72 + k0 + quad * 8];
      }
#pragma unroll
      for (int nt = 0; nt < 8; nt++) {
        bf16x8 bfr = ldfrag(refT, S_N, d0 + nt * 16, k0, lane);
        acc3[0][nt] = MFMA(afr[0], bfr, acc3[0][nt]);
        acc3[1][nt] = MFMA(afr[1], bfr, acc3[1][nt]);
      }
    }
    // direct fp32 stores from C layout: row=batch (quad*4+r), col=d (lane&15)
#pragma unroll
    for (int nt = 0; nt < 8; nt++) {
#pragma unroll
      for (int mt = 0; mt < 2; mt++) {
        int brow = row0 + bbase + mt * 16 + quad * 4;
        int d = d0 + nt * 16 + col;
#pragma unroll
        for (int r = 0; r < 4; r++)
          sel_out[(size_t)(brow + r) * D_N + d] = acc3[mt][nt][r];
      }
    }
  }
}

// ---------------- kernel 2: upd = tanh([x,sel]@wu+bu); accum += sw^T @ upd ----
__global__ __launch_bounds__(256, 2) void k2(
    const float* __restrict__ x, const float* __restrict__ sel, const bf16* __restrict__ wuT,
    const float* __restrict__ bu, const bf16* __restrict__ sw_t, float* __restrict__ accum) {
  __shared__ bf16 updT[128 * 136];  // [d_local][batch]

  const int tid = threadIdx.x;
  const int wave = tid >> 6, lane = tid & 63;
  const int col = lane & 15, quad = lane >> 4;
  const int row0 = blockIdx.x * 128;
  const int bbase = wave * 32;

  for (int c = 0; c < 4; c++) {
    int d0 = c * 128;
    // ---- GEMM4: upd_chunk = [x,sel] @ wu  (M=batch 32/wave, N=128, K=1024)
    f32x4 acc4[2][8];
#pragma unroll
    for (int mt = 0; mt < 2; mt++)
#pragma unroll
      for (int nt = 0; nt < 8; nt++) acc4[mt][nt] = (f32x4){0.f, 0.f, 0.f, 0.f};

    for (int k0 = 0; k0 < 1024; k0 += 32) {
      const float* asrc = (k0 < 512) ? x : sel;
      int kk = k0 & 511;
      bf16x8 afr[2];
#pragma unroll
      for (int mt = 0; mt < 2; mt++)
        afr[mt] = ldfrag_f32(asrc, D_N, row0 + bbase + mt * 16, kk, lane);
#pragma unroll
      for (int nt = 0; nt < 8; nt++) {
        bf16x8 bfr = ldfrag(wuT, 1024, d0 + nt * 16, k0, lane);
        acc4[0][nt] = MFMA(afr[0], bfr, acc4[0][nt]);
        acc4[1][nt] = MFMA(afr[1], bfr, acc4[1][nt]);
      }
    }
    if (c) __syncthreads();  // previous chunk's GEMM5 reads must finish first
    // tanh + bias, store transposed updT[d][batch]
#pragma unroll
    for (int nt = 0; nt < 8; nt++) {
      int dl = nt * 16 + col;
      float bv = bu[d0 + dl];
#pragma unroll
      for (int mt = 0; mt < 2; mt++) {
        int b0 = bbase + mt * 16 + quad * 4;
        bf16x4 pk;
#pragma unroll
        for (int r = 0; r < 4; r++) pk[r] = (bf16)tanhf(acc4[mt][nt][r] + bv);
        *(bf16x4*)&updT[dl * 136 + b0] = pk;
      }
    }
    __syncthreads();

    // ---- GEMM5: partial[s][d] += sw_t[s][i] * updT[d][i]  (M=16/wave, N=128, K=128)
    f32x4 acc5[8];
#pragma unroll
    for (int nt = 0; nt < 8; nt++) acc5[nt] = (f32x4){0.f, 0.f, 0.f, 0.f};
#pragma unroll
    for (int k0 = 0; k0 < 128; k0 += 32) {
      bf16x8 afr = *(const bf16x8*)&sw_t[(size_t)(wave * 16 + col) * B_N + row0 + k0 + quad * 8];
#pragma unroll
      for (int nt = 0; nt < 8; nt++) {
        bf16x8 bfr = *(const bf16x8*)&updT[(nt * 16 + col) * 136 + k0 + quad * 8];
        acc5[nt] = MFMA(afr, bfr, acc5[nt]);
      }
    }
#pragma unroll
    for (int nt = 0; nt < 8; nt++) {
#pragma unroll
      for (int r = 0; r < 4; r++) {
        int st = wave * 16 + quad * 4 + r;
        int d = d0 + nt * 16 + col;
        atomicAdd(&accum[st * D_N + d], acc5[nt][r]);
      }
    }
  }
}

// ---------------- kernel 3: new_ref = ref + LR * accum ----------------
__global__ void k3(const float* __restrict__ ref, const float* __restrict__ accum,
                   float* __restrict__ out2) {
  int i = blockIdx.x * 256 + threadIdx.x;  // 32768 total
  out2[i] = ref[i] + 0.01f * accum[i];
}

extern "C" void kernel_launch(void* const* d_in, const int* in_sizes, int n_in,
                              void* d_out, int out_size, void* d_ws, size_t ws_size,
                              hipStream_t stream) {
  const float* x   = (const float*)d_in[0];
  const float* ref = (const float*)d_in[1];
  const float* w1  = (const float*)d_in[2];
  const float* b1  = (const float*)d_in[3];
  const float* w2  = (const float*)d_in[4];
  const float* b2  = (const float*)d_in[5];
  const float* wu  = (const float*)d_in[6];
  const float* bu  = (const float*)d_in[7];
  float* out_sel = (float*)d_out;
  float* out_ref = out_sel + (size_t)B_N * D_N;

  char* ws = (char*)d_ws;
  bf16*  sw_t  = (bf16*)(ws);                  // 64*131072*2   = 16777216 B
  float* accum = (float*)(ws + 16777216);      // 64*512*4      = 131072 B
  bf16*  w1T   = (bf16*)(ws + 16908288);       // 128*512*2     = 131072 B
  bf16*  w2T   = (bf16*)(ws + 17039360);       // 64*128*2      = 16384 B
  bf16*  refT  = (bf16*)(ws + 17055744);       // 512*64*2      = 65536 B
  bf16*  wuT   = (bf16*)(ws + 17121280);       // 512*1024*2    = 1048576 B

  hipMemsetAsync(accum, 0, S_N * D_N * sizeof(float), stream);
  ktr<<<(512 * 128 + 255) / 256, 256, 0, stream>>>(w1, w1T, 512, 128);
  ktr<<<(128 * 64 + 255) / 256, 256, 0, stream>>>(w2, w2T, 128, 64);
  ktr<<<(64 * 512 + 255) / 256, 256, 0, stream>>>(ref, refT, 64, 512);
  ktr<<<(1024 * 512 + 255) / 256, 256, 0, stream>>>(wu, wuT, 1024, 512);

  k1<<<B_N / 128, 256, 0, stream>>>(x, w1T, b1, w2T, b2, refT, out_sel, sw_t);
  k2<<<B_N / 128, 256, 0, stream>>>(x, out_sel, wuT, bu, sw_t, accum);
  k3<<<S_N * D_N / 256, 256, 0, stream>>>(ref, accum, out_ref);
}